// Round 8
// baseline (680.603 us; speedup 1.0000x reference)
//
#include <hip/hip_runtime.h>
#include <cstddef>
#include <cstdint>

// ---------------------------------------------------------------------------
// SelfAttention: h = softmax(QK^T*scale - 1e9*mask) @ V, p also output.
// B=8, S=2048, F=D=512.
// R10: R9's five kernels -> TWO dispatches:
//   K1 prep (grid 13056): x fp32->bf16, W->W^T bf16, zero barrier counter.
//   K2 attn (grid 256 x 512thr, 128KB LDS => 1 block/CU, all 256 blocks
//      co-resident by construction): projvt -> [devbar] -> QK^T -> [devbar]
//      -> softmax -> [devbar] -> PV. Device barrier = agent-scope
//      atomicAdd(ACQ_REL) + bounded spin + agent acquire fence (emits the
//      cross-XCD L2 writeback/invalidate). Spin guard => a barrier bug
//      FAILS visibly instead of hanging the container (R6 lesson: the
//      cooperative-launch mega died; this avoids hipLaunchCooperativeKernel).
//   All compute sections byte-identical to R9 (461->433 us proven).
//   Purpose: remove 3 more dispatch boundaries (~14us each, measured R9) and
//   get the fused kernel into rocprof's top-5 for real counters.
// ---------------------------------------------------------------------------

typedef __bf16 bf16_t;
typedef __bf16 bf16x8 __attribute__((ext_vector_type(8)));
typedef float f32x4 __attribute__((ext_vector_type(4)));

#define AS1 __attribute__((address_space(1)))
#define AS3 __attribute__((address_space(3)))

__device__ __forceinline__ void gload_lds16(const void* g, void* l) {
  // async global->LDS, 16B/lane; LDS dst = wave-uniform base + lane*16
  __builtin_amdgcn_global_load_lds((AS1 void*)(g), (AS3 void*)(l), 16, 0, 0);
}

#define VMW(n) asm volatile("s_waitcnt vmcnt(" #n ")" ::: "memory")
#define VMS do { if (NF == 4) VMW(6); else VMW(4); } while (0)
#define VM0 VMW(0)

#define MFMA_(a, b, c) __builtin_amdgcn_mfma_f32_16x16x32_bf16(a, b, c, 0, 0, 0)

// LDS fragment reads (byte offsets). A region 32KB each par, B region BREG.
// In-row XOR swizzle on the 16B slot: slot ^= (row & 7).
#define LDA_(par, q, m01, kk) \
  (*(const bf16x8*)(AsB + (par)*32768 + arow + (q)*4096 + (m01)*2048 + offk##kk))
#define LDB_(par, nf, kk) \
  (*(const bf16x8*)(BsB + (par)*BREG + brow + (nf)*2048 + offk##kk))

// One phase: {ds-read frags | stage quarters | [vmcnt] | bar | MFMA | bar}
#define PH(par, q, FIRST, STAGE_STMT, WAIT_STMT)                                 \
  {                                                                              \
    if (FIRST) {                                                                 \
      _Pragma("unroll") for (int nf = 0; nf < NF; ++nf) {                        \
        br[nf][0] = LDB_(par, nf, 0);                                            \
        br[nf][1] = LDB_(par, nf, 1);                                            \
      }                                                                          \
    }                                                                            \
    bf16x8 a00 = LDA_(par, q, 0, 0), a01 = LDA_(par, q, 0, 1);                   \
    bf16x8 a10 = LDA_(par, q, 1, 0), a11 = LDA_(par, q, 1, 1);                   \
    STAGE_STMT;                                                                  \
    WAIT_STMT;                                                                   \
    __builtin_amdgcn_s_barrier();                                                \
    __builtin_amdgcn_s_setprio(1);                                               \
    _Pragma("unroll") for (int nf = 0; nf < NF; ++nf) {                          \
      acc[2*(q)][nf]   = MFMA_(a00, br[nf][0], acc[2*(q)][nf]);                  \
      acc[2*(q)][nf]   = MFMA_(a01, br[nf][1], acc[2*(q)][nf]);                  \
      acc[2*(q)+1][nf] = MFMA_(a10, br[nf][0], acc[2*(q)+1][nf]);                \
      acc[2*(q)+1][nf] = MFMA_(a11, br[nf][1], acc[2*(q)+1][nf]);                \
    }                                                                            \
    __builtin_amdgcn_s_setprio(0);                                               \
    __builtin_amdgcn_s_barrier();                                                \
  }

// One 256xBN output tile of C = A[256,K] * B[BN,K]^T (R7 schedule verbatim).
// Race-free quarter staging; vmcnt ledger verified for NF=2 and NF=4.
template <int NF, bool OUT_BF16>
__device__ __forceinline__ void gemm_tile(
    const bf16_t* __restrict__ Ab, const bf16_t* __restrict__ Bp,
    void* __restrict__ Cp, int ldA, int ldB, int ldC, int K, char* smem) {
  constexpr int BREG = NF * 64 * 128;  // B region bytes (NF2:16K, NF4:32K)
  const int tid = threadIdx.x;
  const int wave = tid >> 6, lane = tid & 63;
  const int wm = wave >> 2, wn = wave & 3;  // 2M x 4N waves
  const int lr = lane & 15, hi = lane >> 4;
  bf16_t* AsE = (bf16_t*)smem;              // 2 x 16384 elems
  bf16_t* BsE = (bf16_t*)(smem + 65536);    // 2 x BREG/2 elems

  auto STGA = [&](int par, int kt, int qi) {
    const int r = tid >> 3, cc = (tid & 7) ^ (r & 7);
    gload_lds16(Ab + (size_t)(qi * 64 + r) * ldA + kt * 64 + cc * 8,
                AsE + par * 16384 + qi * 4096 + wave * 512);
  };
  auto STGB = [&](int par, int kt, int qi) {
    const int r = tid >> 3, cc = (tid & 7) ^ (r & 7);
    gload_lds16(Bp + (size_t)(qi * 64 + r) * ldB + kt * 64 + cc * 8,
                BsE + par * (BREG / 2) + qi * 4096 + wave * 512);
  };

  f32x4 acc[8][NF] = {};
  bf16x8 br[NF][2];
  const char* AsB = smem;
  const char* BsB = smem + 65536;
  const int arow = wm * 16384 + lr * 128;      // bytes
  const int brow = wn * NF * 2048 + lr * 128;  // bytes
  const int swz = (lr & 7) << 4;
  const int offk0 = (hi * 16) ^ swz;
  const int offk1 = (64 + hi * 16) ^ swz;

  const int NITER = K >> 7;  // 2 K-tiles (BK=64) per iteration
  if constexpr (NF == 4) { STGB(0,0,0); STGB(0,0,1); STGB(0,0,2); STGB(0,0,3); }
  else                   { STGB(0,0,0); STGB(0,0,1); }
  STGA(0,0,0); STGA(0,0,1); STGA(0,0,2); STGA(0,0,3);
  if constexpr (NF == 4) { STGB(1,1,0); STGB(1,1,1); STGB(1,1,2); STGB(1,1,3); }
  else                   { STGB(1,1,0); STGB(1,1,1); }
  STGA(1,1,0); STGA(1,1,2);
  VMS;
  __builtin_amdgcn_s_barrier();

  for (int t = 0; t < NITER; ++t) {
    const bool pf = (t + 1 < NITER);
    const int ko = 2*t + 1, ka = 2*t + 2, kb = 2*t + 3;
    PH(0, 0, 1, { STGA(1, ko, 1); STGA(1, ko, 3); }, {});
    PH(0, 1, 0, { if (pf) { STGB(0, ka, 0); STGB(0, ka, 1); } }, {});
    if constexpr (NF == 4) {
      PH(0, 2, 0, { if (pf) { STGB(0, ka, 2); STGB(0, ka, 3); } }, {});
      PH(0, 3, 0, { if (pf) { STGA(0, ka, 0); STGA(0, ka, 2); } },
         { if (pf) VMS; else VM0; });
    } else {
      PH(0, 2, 0, { if (pf) { STGA(0, ka, 0); STGA(0, ka, 2); } }, {});
      PH(0, 3, 0, {}, { if (pf) VMS; else VM0; });
    }
    PH(1, 0, 1, { if (pf) { STGA(0, ka, 1); STGA(0, ka, 3); } }, {});
    PH(1, 1, 0, { if (pf) { STGB(1, kb, 0); STGB(1, kb, 1); } }, {});
    if constexpr (NF == 4) {
      PH(1, 2, 0, { if (pf) { STGB(1, kb, 2); STGB(1, kb, 3); } }, {});
      PH(1, 3, 0, { if (pf) { STGA(1, kb, 0); STGA(1, kb, 2); } }, { if (pf) VMS; });
    } else {
      PH(1, 2, 0, { if (pf) { STGA(1, kb, 0); STGA(1, kb, 2); } }, {});
      PH(1, 3, 0, {}, { if (pf) VMS; });
    }
  }

  // epilogue: C/D layout col = lane&15, row = (lane>>4)*4 + reg
  const int row0 = wm * 128 + hi * 4;
  const int col0 = wn * (16 * NF) + lr;
  if constexpr (OUT_BF16) {
    bf16_t* C = (bf16_t*)Cp;
#pragma unroll
    for (int mf = 0; mf < 8; ++mf)
#pragma unroll
      for (int nf = 0; nf < NF; ++nf)
#pragma unroll
        for (int tt = 0; tt < 4; ++tt)
          C[(size_t)(row0 + mf * 16 + tt) * ldC + col0 + nf * 16] = (bf16_t)acc[mf][nf][tt];
  } else {
    float* C = (float*)Cp;
#pragma unroll
    for (int mf = 0; mf < 8; ++mf)
#pragma unroll
      for (int nf = 0; nf < NF; ++nf)
#pragma unroll
        for (int tt = 0; tt < 4; ++tt)
          C[(size_t)(row0 + mf * 16 + tt) * ldC + col0 + nf * 16] = acc[mf][nf][tt];
  }
}

// Device-scope barrier for 256 co-resident blocks. Monotone counter, agent
// scope (cross-XCD): release-add emits L2 writeback, acquire emits L2
// invalidate. Bounded spin: a logic bug FAILS the test instead of hanging.
__device__ __forceinline__ void grid_barrier(uint32_t* cnt, uint32_t target) {
  __syncthreads();  // all block stores issued & drained (waitcnt 0 + barrier)
  if (threadIdx.x == 0) {
    __hip_atomic_fetch_add(cnt, 1u, __ATOMIC_ACQ_REL, __HIP_MEMORY_SCOPE_AGENT);
    uint32_t guard = 0;
    while (__hip_atomic_load(cnt, __ATOMIC_ACQUIRE, __HIP_MEMORY_SCOPE_AGENT) < target) {
      __builtin_amdgcn_s_sleep(2);
      if (++guard > (1u << 20)) break;  // failsafe: visible FAIL, no hang
    }
  }
  __syncthreads();
  __builtin_amdgcn_fence(__ATOMIC_ACQUIRE, "agent");  // L2 inv for all threads
}

// ---------------------------------------------------------------------------
// K1: x fp32->bf16 (blocks 0..12287) + W -> W^T bf16 (blocks 12288..13055)
//     + zero the device-barrier counter.
// ---------------------------------------------------------------------------
__global__ void prep(const float* __restrict__ qx, const float* __restrict__ kx,
                     const float* __restrict__ vx, const float* __restrict__ Wq,
                     const float* __restrict__ Wk, const float* __restrict__ Wv,
                     bf16_t* __restrict__ Xb, bf16_t* __restrict__ WT,
                     uint32_t* cnt) {
  __shared__ float tile[32][33];
  const int bid = blockIdx.x, tid = threadIdx.x;
  if (bid == 0 && tid == 0)
    __hip_atomic_store(cnt, 0u, __ATOMIC_RELEASE, __HIP_MEMORY_SCOPE_AGENT);
  if (bid < 12288) {
    const int which = bid >> 12;
    const float* in = which == 0 ? qx : (which == 1 ? kx : vx);
    const size_t off = ((size_t)(bid & 4095) * 256 + tid) * 8;
    f32x4 a = *(const f32x4*)(in + off);
    f32x4 b = *(const f32x4*)(in + off + 4);
    bf16x8 o;
#pragma unroll
    for (int j = 0; j < 4; ++j) { o[j] = (bf16_t)a[j]; o[4 + j] = (bf16_t)b[j]; }
    *(bf16x8*)(Xb + (size_t)which * 8388608 + off) = o;
  } else {
    const int w = bid - 12288;                 // 0..767
    const int zz = w >> 8, tj = w & 255;
    const float* W = zz == 0 ? Wq : (zz == 1 ? Wk : Wv);
    const int f0 = (tj >> 4) * 32, d0 = (tj & 15) * 32;
    const int tx = tid & 31, ty = tid >> 5;    // 32 x 8
#pragma unroll
    for (int i = 0; i < 32; i += 8)
      tile[ty + i][tx] = W[(size_t)(f0 + ty + i) * 512 + d0 + tx];
    __syncthreads();
    bf16_t* out = WT + (size_t)zz * 262144;
#pragma unroll
    for (int i = 0; i < 32; i += 8)
      out[(size_t)(d0 + ty + i) * 512 + f0 + tx] = (bf16_t)tile[tx][ty + i];
  }
}

// ---------------------------------------------------------------------------
// K2: persistent fused attention. grid 256 x 512thr, 128KB LDS (1 block/CU
// => all blocks co-resident). Sections separated by grid_barrier.
// ---------------------------------------------------------------------------
__global__ __launch_bounds__(512, 2) void attn(
    const bf16_t* __restrict__ Xb, const bf16_t* __restrict__ WT,
    bf16_t* __restrict__ Q, bf16_t* __restrict__ Vt, bf16_t* __restrict__ s_bf,
    const float* __restrict__ mask, float* __restrict__ p_out,
    float* __restrict__ h_out, uint32_t* cnt) {
  __shared__ __align__(16) char smem[131072];
  const int bid = blockIdx.x, tid = threadIdx.x;

  // ---- S1: Q;K projection (jobs 0..255, BN=256) + Vt (jobs 256..511) ----
#pragma unroll 1
  for (int r = 0; r < 2; ++r) {
    const int job = bid + 256 * r;
    if (job < 256) {  // proj: m 0..127 (stacked q;k rows), n 0..1
      const int m_blk = (job >> 1) * 256, n_blk = (job & 1) * 256;
      const bf16_t* Ab = Xb + (size_t)m_blk * 512;
      const bf16_t* Bp = WT + (m_blk >= 16384 ? (size_t)262144 : 0) + (size_t)n_blk * 512;
      bf16_t* Cp = Q + (size_t)m_blk * 512 + n_blk;
      gemm_tile<4, true>(Ab, Bp, Cp, 512, 512, 512, 512, smem);
    } else {          // Vt: z 0..7, mq 0..1 (D), nq 0..15 (S), BN=128
      const int l = job - 256, zz = l & 7, jj = l >> 3;
      const int mq = jj & 1, nq = jj >> 1;
      const bf16_t* Ab = WT + (size_t)2 * 262144 + (size_t)(mq * 256) * 512;
      const bf16_t* Bp = Xb + (size_t)2 * 8388608 + (size_t)zz * (2048 * 512) +
                         (size_t)(nq * 128) * 512;
      bf16_t* Cp = Vt + (size_t)zz * (512 * 2048) + (size_t)(mq * 256) * 2048 + nq * 128;
      gemm_tile<2, true>(Ab, Bp, Cp, 512, 512, 2048, 512, smem);
    }
    __syncthreads();
  }
  grid_barrier(cnt, 256);

  // ---- S2: QK^T (jobs 0..511, BN=256, batch->XCD; z same both rounds) ---
#pragma unroll 1
  for (int r = 0; r < 2; ++r) {
    const int job = bid + 256 * r;
    const int z = job & 7, j = job >> 3;
    const int m_blk = (j >> 3) * 256, n_blk = (j & 7) * 256;
    const bf16_t* Ab = Q + ((size_t)z * 2048 + m_blk) * 512;
    const bf16_t* Bp = Q + ((size_t)16384 + z * 2048 + n_blk) * 512;
    bf16_t* Cp = s_bf + (size_t)z * 2048 * 2048 + (size_t)m_blk * 2048 + n_blk;
    gemm_tile<4, true>(Ab, Bp, Cp, 512, 512, 2048, 512, smem);
    __syncthreads();
  }
  grid_barrier(cnt, 512);

  // ---- S3: masked softmax, 64 rows/block, 2 rows per pass ---------------
  {
    constexpr float scale = 0.04419417382415922f;  // 1/sqrt(512)
    float* red = (float*)smem;                     // [2][8]
    const int half = tid >> 8, t = tid & 255;
    const int wv = t >> 6, ln = tid & 63;
    const int zz = bid & 7, lb = bid >> 3;
#pragma unroll 1
    for (int p = 0; p < 32; ++p) {
      const size_t row = (size_t)zz * 2048 + lb * 64 + p * 2 + half;
      bf16_t* sr = s_bf + row * 2048;
      float* pr = p_out + row * 2048;
      const float* mr = mask + row * 2048;
      const int c0 = t * 8;
      __syncthreads();  // red reuse guard across passes
      bf16x8 sv = *(const bf16x8*)&sr[c0];
      f32x4 m0 = __builtin_nontemporal_load((const f32x4*)&mr[c0]);
      f32x4 m1 = __builtin_nontemporal_load((const f32x4*)&mr[c0 + 4]);
      float l[8];
      float mx = -3.4e38f;
#pragma unroll
      for (int i = 0; i < 8; ++i) {
        float m = (i < 4) ? m0[i & 3] : m1[i & 3];
        float v = (float)sv[i] * scale + m * (-1e9f);
        l[i] = v;
        mx = fmaxf(mx, v);
      }
      for (int off = 32; off > 0; off >>= 1) mx = fmaxf(mx, __shfl_down(mx, off));
      if (ln == 0) red[half * 8 + wv] = mx;
      __syncthreads();
      mx = fmaxf(fmaxf(red[half * 8 + 0], red[half * 8 + 1]),
                 fmaxf(red[half * 8 + 2], red[half * 8 + 3]));
      float s = 0.f;
#pragma unroll
      for (int i = 0; i < 8; ++i) {
        float e = __expf(l[i] - mx);
        l[i] = e;
        s += e;
      }
      for (int off = 32; off > 0; off >>= 1) s += __shfl_down(s, off);
      if (ln == 0) red[half * 8 + 4 + wv] = s;
      __syncthreads();
      s = red[half * 8 + 4] + red[half * 8 + 5] + red[half * 8 + 6] + red[half * 8 + 7];
      const float inv = 1.f / s;
      f32x4 o0, o1;
      bf16x8 ob;
#pragma unroll
      for (int i = 0; i < 8; ++i) {
        float v = l[i] * inv;
        if (i < 4) o0[i & 3] = v; else o1[i & 3] = v;
        ob[i] = (bf16_t)v;
      }
      __builtin_nontemporal_store(o0, (f32x4*)&pr[c0]);
      __builtin_nontemporal_store(o1, (f32x4*)&pr[c0 + 4]);
      *(bf16x8*)&sr[c0] = ob;  // in-place bf16 p for PV
    }
  }
  grid_barrier(cnt, 768);

  // ---- S4: PV (BN=128, 1 tile/block, batch->XCD; n fastest) -------------
  {
    const int z = bid & 7, j = bid >> 3;
    const int n_blk = (j & 3) * 128, m_blk = (j >> 2) * 256;
    const bf16_t* Ab = s_bf + (size_t)z * 2048 * 2048 + (size_t)m_blk * 2048;
    const bf16_t* Bp = Vt + (size_t)z * 512 * 2048 + (size_t)n_blk * 2048;
    float* Cp = h_out + (size_t)z * 2048 * 512 + (size_t)m_blk * 512 + n_blk;
    gemm_tile<2, false>(Ab, Bp, Cp, 2048, 2048, 512, 2048, smem);
  }
}

extern "C" void kernel_launch(void* const* d_in, const int* in_sizes, int n_in,
                              void* d_out, int out_size, void* d_ws, size_t ws_size,
                              hipStream_t stream) {
  const float* q_x = (const float*)d_in[0];
  const float* k_x = (const float*)d_in[1];
  const float* v_x = (const float*)d_in[2];
  const float* mask = (const float*)d_in[3];
  const float* Wq = (const float*)d_in[4];
  const float* Wk = (const float*)d_in[5];
  const float* Wv = (const float*)d_in[6];

  float* h_out = (float*)d_out;                   // [B,S,D]
  float* p_out = h_out + (size_t)8 * 2048 * 512;  // [B,S,S]

  const size_t BSD = 8388608;                     // 8*2048*512
  const size_t DF = 262144;                       // 512*512
  // ws: [0,256B) barrier counter; then Q;K (2*BSD), Vt (BSD), WT (3*DF),
  // Xb (3*BSD) aliased with s_bf (B*S*S). ~119 MB + 256 B.
  uint32_t* cnt = (uint32_t*)d_ws;
  bf16_t* Q = (bf16_t*)d_ws + 128;                // [32768][512] (q;k rows)
  bf16_t* Vt = Q + 2 * BSD;                       // [8][512][2048]
  bf16_t* WT = Q + 3 * BSD;                       // [3][512][512]
  bf16_t* Xb = WT + 3 * DF;                       // [3][16384][512]
  bf16_t* s_bf = Xb;                              // [8][2048][2048] (alias)

  prep<<<dim3(13056), dim3(256), 0, stream>>>(q_x, k_x, v_x, Wq, Wk, Wv, Xb, WT, cnt);
  attn<<<dim3(256), dim3(512), 0, stream>>>(Xb, WT, Q, Vt, s_bf, mask, p_out,
                                            h_out, cnt);
}